// Round 6
// baseline (399.673 us; speedup 1.0000x reference)
//
#include <hip/hip_runtime.h>
#include <hip/hip_fp16.h>

#define N_NODES 100000
#define N_EDGES 3200000
#define NBK 391          // ceil(N_NODES / 256) buckets, 256 nodes each
#define EPB 8192         // edges per block in binning passes
#define NBLK_BIN 391     // ceil(N_EDGES / EPB)

// ==================== common helpers ====================

__device__ __forceinline__ int wave_incl_scan_i(int v) {
  int lane = threadIdx.x & 63;
#pragma unroll
  for (int off = 1; off < 64; off <<= 1) {
    int n = __shfl_up(v, off);
    if (lane >= off) v += n;
  }
  return v;
}

// unpack uint2 (4 fp16 channels) and accumulate into 4 f32 accumulators
__device__ __forceinline__ void acc4(uint2 u, float& a0, float& a1, float& a2,
                                     float& a3) {
  float2 f01 = __half22float2(*reinterpret_cast<__half2*>(&u.x));
  float2 f23 = __half22float2(*reinterpret_cast<__half2*>(&u.y));
  a0 += f01.x; a1 += f01.y; a2 += f23.x; a3 += f23.y;
}

// ==================== CSR build: bucketed counting sort ====================

__global__ __launch_bounds__(256) void bin_hist(const int* __restrict__ tgt,
                                                int* __restrict__ count) {
  __shared__ int hist[NBK];
  int t = threadIdx.x;
  for (int i = t; i < NBK; i += 256) hist[i] = 0;
  __syncthreads();
  int e0 = blockIdx.x * EPB;
  int e1 = min(e0 + EPB, N_EDGES);
  for (int e = e0 + t; e < e1; e += 256) atomicAdd(&hist[tgt[e] >> 8], 1);
  __syncthreads();
  for (int i = t; i < NBK; i += 256) {
    int c = hist[i];
    if (c) atomicAdd(&count[i], c);
  }
}

__global__ __launch_bounds__(512) void bin_scan(const int* __restrict__ count,
                                                int* __restrict__ bktBase,
                                                int* __restrict__ cursor) {
  __shared__ int lds[8];
  int t = threadIdx.x;
  int v = (t < NBK) ? count[t] : 0;
  int inc = wave_incl_scan_i(v);
  int lane = t & 63, wid = t >> 6;
  if (lane == 63) lds[wid] = inc;
  __syncthreads();
  if (t == 0) {
    int run = 0;
#pragma unroll
    for (int i = 0; i < 8; i++) { int c = lds[i]; lds[i] = run; run += c; }
  }
  __syncthreads();
  int ex = inc - v + lds[wid];
  if (t < NBK) { bktBase[t] = ex; cursor[t] = ex; }
  if (t == NBK) bktBase[NBK] = ex;  // == N_EDGES
}

__global__ __launch_bounds__(256) void bin_scatter(const int* __restrict__ src,
                                                   const int* __restrict__ tgt,
                                                   int* __restrict__ cursor,
                                                   unsigned int* __restrict__ binned) {
  __shared__ int hist[NBK];
  __shared__ int lbase[NBK];
  int t = threadIdx.x;
  for (int i = t; i < NBK; i += 256) hist[i] = 0;
  __syncthreads();
  int e0 = blockIdx.x * EPB;
  int e1 = min(e0 + EPB, N_EDGES);
  for (int e = e0 + t; e < e1; e += 256) atomicAdd(&hist[tgt[e] >> 8], 1);
  __syncthreads();
  for (int i = t; i < NBK; i += 256) {
    int c = hist[i];
    lbase[i] = c ? atomicAdd(&cursor[i], c) : 0;
    hist[i] = 0;  // reuse as local cursor
  }
  __syncthreads();
  for (int e = e0 + t; e < e1; e += 256) {
    int tg = tgt[e];
    int bkt = tg >> 8;
    int lo = atomicAdd(&hist[bkt], 1);
    binned[lbase[bkt] + lo] = (unsigned int)src[e] | ((unsigned int)(tg & 255) << 17);
  }
}

__global__ __launch_bounds__(256) void bucket_sort(const unsigned int* __restrict__ binned,
                                                   const int* __restrict__ bktBase,
                                                   int* __restrict__ csr,
                                                   int* __restrict__ offs) {
  __shared__ int deg[256];
  __shared__ int lcur[256];
  __shared__ int wsum[4];
  int b = blockIdx.x;
  int t = threadIdx.x;
  int base = bktBase[b];
  int cnt = bktBase[b + 1] - base;
  deg[t] = 0;
  __syncthreads();
  for (int i = t; i < cnt; i += 256) atomicAdd(&deg[binned[base + i] >> 17], 1);
  __syncthreads();
  int v = deg[t];
  int inc = wave_incl_scan_i(v);
  int lane = t & 63, wid = t >> 6;
  if (lane == 63) wsum[wid] = inc;
  __syncthreads();
  if (t == 0) {
    int run = 0;
#pragma unroll
    for (int i = 0; i < 4; i++) { int c = wsum[i]; wsum[i] = run; run += c; }
  }
  __syncthreads();
  int incl = inc + wsum[wid];
  lcur[t] = base + incl - v;  // exclusive start
  int node = b * 256 + t;
  if (node < N_NODES) offs[node] = base + incl;  // end position
  __syncthreads();
  for (int i = t; i < cnt; i += 256) {
    unsigned int pv = binned[base + i];
    int pos = atomicAdd(&lcur[pv >> 17], 1);
    csr[pos] = (int)(pv & 0x1FFFFu);
  }
}

// ==================== fp16 conversion ====================

__global__ __launch_bounds__(256) void to_half2(const float* __restrict__ in,
                                                __half2* __restrict__ out, int n2) {
  int i = blockIdx.x * 256 + threadIdx.x;
  if (i >= n2) return;
  float2 v = reinterpret_cast<const float2*>(in)[i];
  out[i] = __floats2half2_rn(v.x, v.y);
}

// ==================== fused layers (CSR path, fp16, uint2 gathers) ====================

// Layer 1: wave per node. x fp16: row = 8 uint2 (32 ch). Eighth-wave (8 lanes)
// per row -> 8 rows per wave instr; unroll 4 -> 32 rows in flight.
// lane = e*8 + c8: c8 covers channels 4c8..4c8+3, e = edge phase.
__global__ __launch_bounds__(256) void layer1_fused(
    const uint2* __restrict__ xq, const int* __restrict__ csr,
    const int* __restrict__ offs, const float* __restrict__ Wl,
    const float* __restrict__ Wr, const float* __restrict__ b,
    const float* __restrict__ g, const float* __restrict__ be,
    __half* __restrict__ h1) {
  int node = blockIdx.x * 4 + (threadIdx.x >> 6);
  if (node >= N_NODES) return;
  int lane = threadIdx.x & 63;
  int c8 = lane & 7, e = lane >> 3;

  int end = offs[node];
  int start = node ? offs[node - 1] : 0;
  float inv = 1.0f / fmaxf((float)(end - start), 1.0f);

  float a0 = 0.f, a1 = 0.f, a2 = 0.f, a3 = 0.f;
  int slot = start + e;
  for (; slot + 24 < end; slot += 32) {
    int s0 = csr[slot], s1 = csr[slot + 8], s2 = csr[slot + 16], s3 = csr[slot + 24];
    uint2 u0 = xq[(size_t)s0 * 8 + c8];
    uint2 u1 = xq[(size_t)s1 * 8 + c8];
    uint2 u2 = xq[(size_t)s2 * 8 + c8];
    uint2 u3 = xq[(size_t)s3 * 8 + c8];
    acc4(u0, a0, a1, a2, a3);
    acc4(u1, a0, a1, a2, a3);
    acc4(u2, a0, a1, a2, a3);
    acc4(u3, a0, a1, a2, a3);
  }
  for (; slot < end; slot += 8) {
    uint2 u = xq[(size_t)csr[slot] * 8 + c8];
    acc4(u, a0, a1, a2, a3);
  }
  // reduce across the 8 edge-phases (bits 3,4,5 of lane)
#pragma unroll
  for (int off = 8; off < 64; off <<= 1) {
    a0 += __shfl_xor(a0, off);
    a1 += __shfl_xor(a1, off);
    a2 += __shfl_xor(a2, off);
    a3 += __shfl_xor(a3, off);
  }

  uint2 us = xq[(size_t)node * 8 + c8];
  float2 s01 = __half22float2(*reinterpret_cast<__half2*>(&us.x));
  float2 s23 = __half22float2(*reinterpret_cast<__half2*>(&us.y));

  int o = lane;
  float accO = b[o];
#pragma unroll
  for (int k = 0; k < 32; k++) {
    const int sl = k >> 2, j = k & 3;
    float ak = __shfl(j == 0 ? a0 : j == 1 ? a1 : j == 2 ? a2 : a3, sl);
    float xk = __shfl(j == 0 ? s01.x : j == 1 ? s01.y : j == 2 ? s23.x : s23.y, sl);
    accO = fmaf(ak * inv, Wl[k * 64 + o], accO);
    accO = fmaf(xk, Wr[k * 64 + o], accO);
  }

  // LayerNorm over 64 lanes + ReLU
  float s = accO;
#pragma unroll
  for (int off = 32; off; off >>= 1) s += __shfl_xor(s, off);
  float mu = s * (1.0f / 64.0f);
  float d = accO - mu;
  float v2 = d * d;
#pragma unroll
  for (int off = 32; off; off >>= 1) v2 += __shfl_xor(v2, off);
  float o2 = d * rsqrtf(v2 * (1.0f / 64.0f) + 1e-5f) * g[o] + be[o];
  h1[(size_t)node * 64 + o] = __float2half(fmaxf(o2, 0.0f));
}

// Layer 2 (+ fused layer-3 node part): wave per node. h1 fp16: row = 16 uint2
// (64 ch). Quarter-wave (16 lanes) per row -> 4 rows per wave instr; unroll 4
// -> 16 rows in flight. Epilogue keeps h2 in registers: computes
// y3 = h2 @ W_l3 (staged for gather3) and out_self = h2 @ W_r3 + b3.
__global__ __launch_bounds__(256) void layer2_fused(
    const uint2* __restrict__ h1q, const int* __restrict__ csr,
    const int* __restrict__ offs, const float* __restrict__ Wl,
    const float* __restrict__ Wr, const float* __restrict__ b,
    const float* __restrict__ g, const float* __restrict__ be,
    const float* __restrict__ Wl3, const float* __restrict__ Wr3,
    const float* __restrict__ b3, float* __restrict__ y3,
    float* __restrict__ out) {
  int node = blockIdx.x * 4 + (threadIdx.x >> 6);
  if (node >= N_NODES) return;
  int lane = threadIdx.x & 63;
  int cq = lane & 15, q = lane >> 4;

  int end = offs[node];
  int start = node ? offs[node - 1] : 0;
  float inv = 1.0f / fmaxf((float)(end - start), 1.0f);

  float a0 = 0.f, a1 = 0.f, a2 = 0.f, a3 = 0.f;
  int slot = start + q;
  for (; slot + 12 < end; slot += 16) {
    int s0 = csr[slot], s1 = csr[slot + 4], s2 = csr[slot + 8], s3 = csr[slot + 12];
    uint2 u0 = h1q[(size_t)s0 * 16 + cq];
    uint2 u1 = h1q[(size_t)s1 * 16 + cq];
    uint2 u2 = h1q[(size_t)s2 * 16 + cq];
    uint2 u3 = h1q[(size_t)s3 * 16 + cq];
    acc4(u0, a0, a1, a2, a3);
    acc4(u1, a0, a1, a2, a3);
    acc4(u2, a0, a1, a2, a3);
    acc4(u3, a0, a1, a2, a3);
  }
  for (; slot < end; slot += 4) {
    uint2 u = h1q[(size_t)csr[slot] * 16 + cq];
    acc4(u, a0, a1, a2, a3);
  }
  // reduce across the 4 quarters (bits 4,5 of lane)
#pragma unroll
  for (int off = 16; off < 64; off <<= 1) {
    a0 += __shfl_xor(a0, off);
    a1 += __shfl_xor(a1, off);
    a2 += __shfl_xor(a2, off);
    a3 += __shfl_xor(a3, off);
  }

  uint2 us = h1q[(size_t)node * 16 + cq];
  float2 s01 = __half22float2(*reinterpret_cast<__half2*>(&us.x));
  float2 s23 = __half22float2(*reinterpret_cast<__half2*>(&us.y));

  int o = lane;
  float accO = b[o];
#pragma unroll
  for (int k = 0; k < 64; k++) {
    const int sl = k >> 2, j = k & 3;
    float ak = __shfl(j == 0 ? a0 : j == 1 ? a1 : j == 2 ? a2 : a3, sl);
    float hk = __shfl(j == 0 ? s01.x : j == 1 ? s01.y : j == 2 ? s23.x : s23.y, sl);
    accO = fmaf(ak * inv, Wl[k * 64 + o], accO);
    accO = fmaf(hk, Wr[k * 64 + o], accO);
  }

  float s = accO;
#pragma unroll
  for (int off = 32; off; off >>= 1) s += __shfl_xor(s, off);
  float mu = s * (1.0f / 64.0f);
  float d = accO - mu;
  float v2 = d * d;
#pragma unroll
  for (int off = 32; off; off >>= 1) v2 += __shfl_xor(v2, off);
  float h2v = fmaxf(d * rsqrtf(v2 * (1.0f / 64.0f) + 1e-5f) * g[o] + be[o], 0.0f);

  // fused layer-3 node part: lane o holds h2[o]
  float t0 = h2v * Wl3[o * 2 + 0];
  float t1 = h2v * Wl3[o * 2 + 1];
  float t2 = h2v * Wr3[o * 2 + 0];
  float t3 = h2v * Wr3[o * 2 + 1];
#pragma unroll
  for (int off = 32; off; off >>= 1) {
    t0 += __shfl_xor(t0, off);
    t1 += __shfl_xor(t1, off);
    t2 += __shfl_xor(t2, off);
    t3 += __shfl_xor(t3, off);
  }
  if (lane == 0) {
    reinterpret_cast<float2*>(y3)[node] = make_float2(t0, t1);
    reinterpret_cast<float2*>(out)[node] = make_float2(t2 + b3[0], t3 + b3[1]);
  }
}

// Layer 3 gather: wave per node, edges strided across lanes, shfl reduce.
__global__ __launch_bounds__(256) void gather3(
    const float* __restrict__ y, const int* __restrict__ csr,
    const int* __restrict__ offs, float* __restrict__ out) {
  int node = blockIdx.x * 4 + (threadIdx.x >> 6);
  if (node >= N_NODES) return;
  int lane = threadIdx.x & 63;

  int end = offs[node];
  int start = node ? offs[node - 1] : 0;
  float inv = 1.0f / fmaxf((float)(end - start), 1.0f);

  float s0 = 0.f, s1 = 0.f;
  for (int slot = start + lane; slot < end; slot += 64) {
    float2 v = reinterpret_cast<const float2*>(y)[csr[slot]];
    s0 += v.x;
    s1 += v.y;
  }
#pragma unroll
  for (int off = 32; off; off >>= 1) {
    s0 += __shfl_xor(s0, off);
    s1 += __shfl_xor(s1, off);
  }
  if (lane == 0) {
    out[(size_t)node * 2 + 0] += s0 * inv;
    out[(size_t)node * 2 + 1] += s1 * inv;
  }
}

// ==================== launch ====================

extern "C" void kernel_launch(void* const* d_in, const int* in_sizes, int n_in,
                              void* d_out, int out_size, void* d_ws, size_t ws_size,
                              hipStream_t stream) {
  const float* x = (const float*)d_in[0];
  const int* ei = (const int*)d_in[1];
  const int* src = ei;
  const int* tgt = ei + N_EDGES;
  const float* Wl1 = (const float*)d_in[2];
  const float* Wr1 = (const float*)d_in[3];
  const float* b1 = (const float*)d_in[4];
  const float* g1 = (const float*)d_in[5];
  const float* be1 = (const float*)d_in[6];
  const float* Wl2 = (const float*)d_in[7];
  const float* Wr2 = (const float*)d_in[8];
  const float* b2 = (const float*)d_in[9];
  const float* g2 = (const float*)d_in[10];
  const float* be2 = (const float*)d_in[11];
  const float* Wl3 = (const float*)d_in[12];
  const float* Wr3 = (const float*)d_in[13];
  const float* b3 = (const float*)d_in[14];
  float* out = (float*)d_out;
  char* ws = (char*)d_ws;

  // ---- workspace layout (~33 MB) ----
  size_t p = 0;
  auto carve = [&](size_t bytes) {
    size_t r = p;
    p += (bytes + 255) & ~(size_t)255;
    return r;
  };
  size_t count_off = carve((size_t)NBK * 4);
  size_t base_off = carve((size_t)(NBK + 1) * 4);
  size_t cursor_off = carve((size_t)NBK * 4);
  size_t offs_off = carve((size_t)N_NODES * 4);
  size_t csr_off = carve((size_t)N_EDGES * 4);
  size_t xh_off = carve((size_t)N_NODES * 32 * 2);  // x fp16; later y3 (800KB)
  size_t h1_off = carve((size_t)N_NODES * 64 * 2);  // h1 fp16; binned aliases (12.8MB)

  int* count = (int*)(ws + count_off);
  int* bktBase = (int*)(ws + base_off);
  int* cursor = (int*)(ws + cursor_off);
  int* offs = (int*)(ws + offs_off);
  int* csr = (int*)(ws + csr_off);
  __half2* xh = (__half2*)(ws + xh_off);
  __half* h1 = (__half*)(ws + h1_off);
  unsigned int* binned = (unsigned int*)h1;  // dead before h1 is written

  hipMemsetAsync(count, 0, (size_t)NBK * 4, stream);
  bin_hist<<<NBLK_BIN, 256, 0, stream>>>(tgt, count);
  bin_scan<<<1, 512, 0, stream>>>(count, bktBase, cursor);
  bin_scatter<<<NBLK_BIN, 256, 0, stream>>>(src, tgt, cursor, binned);
  bucket_sort<<<NBK, 256, 0, stream>>>(binned, bktBase, csr, offs);

  to_half2<<<(N_NODES * 16 + 255) / 256, 256, 0, stream>>>(x, xh, N_NODES * 16);

  layer1_fused<<<(N_NODES + 3) / 4, 256, 0, stream>>>(
      (const uint2*)xh, csr, offs, Wl1, Wr1, b1, g1, be1, h1);

  float* y3 = (float*)xh;  // xh dead after layer1; reuse (800KB)
  layer2_fused<<<(N_NODES + 3) / 4, 256, 0, stream>>>(
      (const uint2*)h1, csr, offs, Wl2, Wr2, b2, g2, be2, Wl3, Wr3, b3, y3, out);

  gather3<<<(N_NODES + 3) / 4, 256, 0, stream>>>(y3, csr, offs, out);
}